// Round 8
// baseline (122.353 us; speedup 1.0000x reference)
//
#include <hip/hip_runtime.h>
#include <hip/hip_bf16.h>

#define BATCH 4
#define SEQ 4096
#define DMODEL 2048
#define HD 128
#define BS (BATCH*SEQ)

typedef __attribute__((ext_vector_type(8))) short short8;
typedef __attribute__((ext_vector_type(4))) short short4v;
typedef __attribute__((ext_vector_type(4))) float f32x4;
typedef __attribute__((ext_vector_type(4))) float float4v;
typedef unsigned short u16;
typedef unsigned int u32;

#define LOG2E 1.4426950408889634f
#define SCALE 0.08838834764831845f /* 1/sqrt(128) */

__device__ __forceinline__ u16 f2bf(float f){
  u32 u = __builtin_bit_cast(u32, f);
  u32 r = (u + 0x7FFFu + ((u >> 16) & 1u)) >> 16;
  return (u16)r;
}

__device__ __forceinline__ void gload16(const void* gptr, void* lptr){
  __builtin_amdgcn_global_load_lds((const __attribute__((address_space(1))) void*)gptr,
                                   (__attribute__((address_space(3))) void*)lptr, 16, 0, 0);
}

// ---------------- trig table: tab[s*64+j] = (cos, sin)(s * 10000^(-j/64)) ----------------
__global__ __launch_bounds__(256) void k_tab(float2* __restrict__ tab){
  int i = blockIdx.x*256 + threadIdx.x;      // 4096*64 total
  int s = i >> 6, j = i & 63;
  float invf = (float)pow(10000.0, -(double)j/64.0);
  float ang  = (float)s * invf;              // mimic fp32 reference rounding of the angle
  double a = (double)ang;
  tab[i] = make_float2((float)cos(a), (float)sin(a));
}

// ---------------- weights fp32 -> bf16 (wq|wk|wv packed) ----------------
__global__ __launch_bounds__(256) void k_cvtw(const float* __restrict__ wq, const float* __restrict__ wk,
                                              const float* __restrict__ wv, u16* __restrict__ wb){
  int i = blockIdx.x*256 + threadIdx.x;      // 3*262144 total
  int m = i >> 18; int r = i & 262143;
  const float* s = (m==0) ? wq : ((m==1) ? wk : wv);
  wb[i] = f2bf(s[r]);
}

// ---------------- fused QKV projection GEMM (fp32 x, cvt fused) + RoPE / V^T epilogue -----
// m97 structure: BM=128, BN=128 (ng=Q/K/V), BK=64, grid 384, 4 waves x (32x128).
// LDS 32KB single-buffered, two plain __syncthreads per K-step, NO manual scheduling.
// A: 8 coalesced float4 loads -> cvt once -> 8 swizzled ds_write_b64.
// W: 4 preswizzled global_load_lds (width 16).
// bid->(xcd, idx): 3 ng-blocks of an M-tile are consecutive on one XCD (x L2-shared).
__global__ __launch_bounds__(256,2) void k_gemm(
    const float* __restrict__ x, const u16* __restrict__ wb, const float2* __restrict__ tab,
    u16* __restrict__ qb, u16* __restrict__ kb, u16* __restrict__ vt)
{
  __shared__ char lds[32768];   // [0,16K) A bf16 128x64 swz; [16K,32K) W bf16 128x64 swz
  const int tid = threadIdx.x;
  const int bid = blockIdx.x;
  const int xcd = bid & 7, idx = bid >> 3;   // 48 blocks per XCD
  const int mloc = idx / 3, ng = idx - mloc*3;
  const int mg = xcd*16 + mloc;              // 0..127
  const size_t M0 = (size_t)mg * 128;
  const u16* Wm = wb + (size_t)ng * (HD*DMODEL);
  const int w = tid >> 6, lane = tid & 63, lr = lane & 15, lg = lane >> 4;

  // A staging addresses: chunk i covers L = i*4096 + tid*16 of the 128x64 fp32 tile
  const float* aptr[8];
  int awb[8];
  #pragma unroll
  for (int i=0;i<8;i++){
    int L = i*4096 + tid*16;
    int row = L >> 8, col = (L & 255) >> 2;
    aptr[i] = x + (M0 + row)*DMODEL + col;
    awb[i]  = row*128 + ((col*2) ^ ((row & 7) << 4));
  }
  // W staging: 4 gload16/thread, preswizzled source
  int woff[4], wdst[4];
  #pragma unroll
  for (int i=0;i<4;i++){
    int L = i*4096 + tid*16;
    int row = L >> 7, cb = L & 127;
    int scb = cb ^ ((row & 7) << 4);
    woff[i] = row*DMODEL + (scb >> 1);
    wdst[i] = 16384 + L;
  }

  f32x4 acc[2][8];
  #pragma unroll
  for (int i=0;i<2;i++)
    #pragma unroll
    for (int j=0;j<8;j++) acc[i][j] = f32x4{0.f,0.f,0.f,0.f};

  for (int t=0; t<32; t++){
    const int k0 = t*64;
    // stage: A fp32 loads (coalesced 1KB/instr), W DMA, cvt+write A
    float4v av[8];
    #pragma unroll
    for (int i=0;i<8;i++) av[i] = *(const float4v*)(aptr[i] + k0);
    #pragma unroll
    for (int i=0;i<4;i++) gload16(Wm + woff[i] + k0, lds + wdst[i]);
    #pragma unroll
    for (int i=0;i<8;i++){
      short4v o;
      o[0]=(short)f2bf(av[i][0]); o[1]=(short)f2bf(av[i][1]);
      o[2]=(short)f2bf(av[i][2]); o[3]=(short)f2bf(av[i][3]);
      *(short4v*)(lds + awb[i]) = o;
    }
    __syncthreads();
    // compute
    short8 afr[2][2], bfr[8][2];
    #pragma unroll
    for (int rf=0; rf<2; rf++)
      #pragma unroll
      for (int ks=0; ks<2; ks++){
        int r = w*32 + rf*16 + lr;
        afr[rf][ks] = *(const short8*)(lds + r*128 + ((ks*64 + lg*16) ^ ((r&7)<<4)));
      }
    #pragma unroll
    for (int nf=0; nf<8; nf++)
      #pragma unroll
      for (int ks=0; ks<2; ks++){
        int r = nf*16 + lr;
        bfr[nf][ks] = *(const short8*)(lds + 16384 + r*128 + ((ks*64 + lg*16) ^ ((r&7)<<4)));
      }
    #pragma unroll
    for (int rf=0; rf<2; rf++)
      #pragma unroll
      for (int nf=0; nf<8; nf++){
        acc[rf][nf] = __builtin_amdgcn_mfma_f32_16x16x32_bf16(afr[rf][0], bfr[nf][0], acc[rf][nf], 0,0,0);
        acc[rf][nf] = __builtin_amdgcn_mfma_f32_16x16x32_bf16(afr[rf][1], bfr[nf][1], acc[rf][nf], 0,0,0);
      }
    __syncthreads();
  }

  if (ng < 2){
    u16* dst = (ng == 0) ? qb : kb;
    #pragma unroll
    for (int rf=0; rf<2; rf++){
      #pragma unroll
      for (int reg=0; reg<4; reg++){
        size_t grow = M0 + w*32 + rf*16 + lg*4 + reg;
        int spos = (int)(grow & (SEQ-1));
        #pragma unroll
        for (int cf=0; cf<4; cf++){
          int j = cf*16 + lr;                 // 0..63
          float2 cs = tab[spos*64 + j];
          float lo = acc[rf][cf][reg];
          float hi = acc[rf][cf+4][reg];
          dst[grow*HD + j]      = f2bf(lo*cs.x - hi*cs.y);
          dst[grow*HD + j + 64] = f2bf(hi*cs.x + lo*cs.y);
        }
      }
    }
  } else {
    #pragma unroll
    for (int rf=0; rf<2; rf++)
      #pragma unroll
      for (int reg=0; reg<4; reg++){
        size_t grow = M0 + w*32 + rf*16 + lg*4 + reg;
        size_t b = grow >> 12;
        size_t spos = grow & (SEQ-1);
        #pragma unroll
        for (int cf=0; cf<8; cf++){
          int col = cf*16 + lr;
          vt[(b*HD + col)*SEQ + spos] = f2bf(acc[rf][cf][reg]);
        }
      }
  }
}

// ---------------- causal flash attention, 4-way KV split (flash-decoding) ----------------
// grid 1024: (batch, 64-row q-tile, kv-split). 4 waves x 16 q-rows share staged lK/lV.
// LDS 40KB -> 4 blocks/CU -> 16 waves/CU. qt descending (heavy first);
// bid&7 -> XCD pairs per batch so each XCD's L2 holds one batch's K+V (2MB).
__global__ __launch_bounds__(256) void k_attn(
    const u16* __restrict__ qbuf, const u16* __restrict__ kb, const u16* __restrict__ vt,
    float* __restrict__ Opart, float2* __restrict__ ml)
{
  __shared__ u16 lK[64*128];    // byte = kv*256 + (cb ^ ((kv&7)<<4))
  __shared__ u16 lV[128*64];    // byte = d*128  + (cb ^ ((d&7)<<4))
  __shared__ u16 lP[4][16*64];  // per-wave, byte = r*128 + (cb ^ ((r&7)<<4))
  const int tid = threadIdx.x;
  const int bid = blockIdx.x;
  const int x = bid & 7, idx = bid >> 3;
  const int b = x >> 1, half = x & 1;
  const int qt = 63 - (idx >> 1);              // heavy tiles first
  const int sp = (idx & 1) + 2*half;           // kv-split 0..3
  const int qbn = b*64 + qt;                   // 0..255
  const int w = tid >> 6, lane = tid & 63, lr = lane & 15, lg = lane >> 4;

  // balanced contiguous partition of tiles [0, qt] into 4 chunks
  const int n = qt + 1, cbase = n >> 2, crem = n & 3;
  const int cnt = cbase + (sp < crem ? 1 : 0);
  const int klo = sp*cbase + (sp < crem ? sp : crem);
  const int khi = klo + cnt;
  const size_t prow0 = ((size_t)qbn*4 + sp)*64;

  if (cnt == 0){                               // empty split: mark and exit (block-uniform)
    if (lr == 0){
      #pragma unroll
      for (int reg=0; reg<4; reg++)
        ml[prow0 + w*16 + lg*4 + reg] = make_float2(-1e30f, 0.f);
    }
    return;
  }

  const size_t qrow = (size_t)b*SEQ + qt*64 + w*16 + lr;
  short8 aq[4];
  #pragma unroll
  for (int ks=0; ks<4; ks++)
    aq[ks] = *(const short8*)(qbuf + qrow*HD + ks*32 + lg*8);

  f32x4 accO[8];
  #pragma unroll
  for (int i=0;i<8;i++) accO[i] = f32x4{0.f,0.f,0.f,0.f};
  float m2[4]   = {-1e30f,-1e30f,-1e30f,-1e30f};
  float lsum[4] = {0.f,0.f,0.f,0.f};

  const int Lb = tid*16;
  const float cfac = SCALE * LOG2E;

  for (int kt = klo; kt < khi; kt++){
    #pragma unroll
    for (int i=0;i<4;i++){
      int L = i*4096 + Lb;
      { int row = L >> 8, cb = L & 255;
        int scb = cb ^ ((row & 7) << 4);
        gload16(kb + ((size_t)b*SEQ + kt*64 + row)*HD + (scb>>1), ((char*)lK) + L); }
      { int row = L >> 7, cb = L & 127;
        int scb = cb ^ ((row & 7) << 4);
        gload16(vt + ((size_t)b*HD + row)*SEQ + kt*64 + (scb>>1), ((char*)lV) + L); }
    }
    __syncthreads();

    // S = Q K^T  (16 q-rows x 64 kv) in log2-domain units
    f32x4 sc[4];
    #pragma unroll
    for (int nf=0; nf<4; nf++){
      sc[nf] = f32x4{0.f,0.f,0.f,0.f};
      #pragma unroll
      for (int ks=0; ks<4; ks++){
        int r = nf*16 + lr;
        int byte = r*256 + ((ks*64 + lg*16) ^ ((r&7)<<4));
        short8 bk = *(const short8*)((const char*)lK + byte);
        sc[nf] = __builtin_amdgcn_mfma_f32_16x16x32_bf16(aq[ks], bk, sc[nf], 0,0,0);
      }
      sc[nf] *= cfac;
    }
    if (kt == qt){                            // diagonal tile: causal mask
      #pragma unroll
      for (int nf=0; nf<4; nf++)
        #pragma unroll
        for (int reg=0; reg<4; reg++){
          int col = nf*16 + lr;
          int row = w*16 + lg*4 + reg;
          if (col > row) sc[nf][reg] = -1e30f;
        }
    }
    float al[4];
    #pragma unroll
    for (int reg=0; reg<4; reg++){
      float v = fmaxf(fmaxf(sc[0][reg], sc[1][reg]), fmaxf(sc[2][reg], sc[3][reg]));
      v = fmaxf(v, __shfl_xor(v, 1));
      v = fmaxf(v, __shfl_xor(v, 2));
      v = fmaxf(v, __shfl_xor(v, 4));
      v = fmaxf(v, __shfl_xor(v, 8));
      float mnew = fmaxf(m2[reg], v);
      al[reg] = exp2f(m2[reg] - mnew);
      m2[reg] = mnew;
    }
    float prs[4] = {0.f,0.f,0.f,0.f};
    #pragma unroll
    for (int nf=0; nf<4; nf++)
      #pragma unroll
      for (int reg=0; reg<4; reg++){
        float p = exp2f(sc[nf][reg] - m2[reg]);
        prs[reg] += p;
        int r = lg*4 + reg;
        int byte = r*128 + ((nf*32 + lr*2) ^ ((r&7)<<4));
        *(u16*)(((char*)lP[w]) + byte) = f2bf(p);
      }
    f32x4 alv = f32x4{al[0], al[1], al[2], al[3]};
    #pragma unroll
    for (int reg=0; reg<4; reg++){
      float v = prs[reg];
      v += __shfl_xor(v, 1);
      v += __shfl_xor(v, 2);
      v += __shfl_xor(v, 4);
      v += __shfl_xor(v, 8);
      lsum[reg] = lsum[reg]*al[reg] + v;
    }
    #pragma unroll
    for (int cf=0; cf<8; cf++) accO[cf] *= alv;

    short8 pa[2];
    #pragma unroll
    for (int ks=0; ks<2; ks++){
      int byte = lr*128 + ((ks*64 + lg*16) ^ ((lr&7)<<4));
      pa[ks] = *(const short8*)(((const char*)lP[w]) + byte);
    }
    #pragma unroll
    for (int cf=0; cf<8; cf++){
      #pragma unroll
      for (int ks=0; ks<2; ks++){
        int d = cf*16 + lr;
        int byte = d*128 + ((ks*64 + lg*16) ^ ((d&7)<<4));
        short8 bv = *(const short8*)(((const char*)lV) + byte);
        accO[cf] = __builtin_amdgcn_mfma_f32_16x16x32_bf16(pa[ks], bv, accO[cf], 0,0,0);
      }
    }
    __syncthreads();
  }

  // partial epilogue: raw accO + (m, l) per row
  #pragma unroll
  for (int reg=0; reg<4; reg++){
    size_t pr = prow0 + w*16 + lg*4 + reg;
    #pragma unroll
    for (int cf=0; cf<8; cf++)
      Opart[pr*HD + cf*16 + lr] = accO[cf][reg];
  }
  if (lr == 0){
    #pragma unroll
    for (int reg=0; reg<4; reg++)
      ml[prow0 + w*16 + lg*4 + reg] = make_float2(m2[reg], lsum[reg]);
  }
}

// ---------------- combine partials: out = sum_s O_s * 2^(m_s-M) / L ----------------
__global__ __launch_bounds__(256) void k_comb(
    const float* __restrict__ Opart, const float2* __restrict__ ml, float* __restrict__ out)
{
  const int t = threadIdx.x;
  const int r = blockIdx.x*8 + (t >> 5);       // global row 0..16383
  const int c = (t & 31)*4;
  const int qbn = r >> 6, rr = r & 63;
  float m[4], l[4], M = -1e30f;
  #pragma unroll
  for (int s=0; s<4; s++){
    float2 v = ml[((size_t)qbn*4 + s)*64 + rr];
    m[s] = v.x; l[s] = v.y;
    M = fmaxf(M, m[s]);
  }
  float L = 0.f;
  #pragma unroll
  for (int s=0; s<4; s++){ m[s] = exp2f(m[s] - M); L += l[s]*m[s]; }
  const float inv = 1.0f / L;
  f32x4 acc = f32x4{0.f,0.f,0.f,0.f};
  #pragma unroll
  for (int s=0; s<4; s++){
    f32x4 o = *(const f32x4*)(Opart + (((size_t)qbn*4 + s)*64 + rr)*(size_t)HD + c);
    float sc = m[s]*inv;
    acc += o * sc;
  }
  *(f32x4*)(out + (size_t)r*HD + c) = acc;
}

extern "C" void kernel_launch(void* const* d_in, const int* in_sizes, int n_in,
                              void* d_out, int out_size, void* d_ws, size_t ws_size,
                              hipStream_t stream){
  const float* x  = (const float*)d_in[0];
  const float* wq = (const float*)d_in[1];
  const float* wk = (const float*)d_in[2];
  const float* wv = (const float*)d_in[3];
  float* out = (float*)d_out;
  char* ws = (char*)d_ws;

  size_t off = 0;
  u16* wb = (u16*)(ws + off); off += (size_t)3*HD*DMODEL*2;     // 1.5 MB
  float2* tab = (float2*)(ws + off); off += (size_t)SEQ*64*8;   // 2 MB
  u16* qb = (u16*)(ws + off); off += (size_t)BS*HD*2;           // 4 MB
  u16* kb = (u16*)(ws + off); off += (size_t)BS*HD*2;           // 4 MB
  u16* vt = (u16*)(ws + off); off += (size_t)BS*HD*2;           // 4 MB
  float* Opart = (float*)(ws + off); off += (size_t)1024*64*HD*4; // 33.5 MB
  float2* ml   = (float2*)(ws + off); off += (size_t)1024*64*8;   // 0.5 MB
  if (ws_size < off) return;  // insufficient workspace -> fail visibly

  hipLaunchKernelGGL(k_tab,  dim3(1024),  dim3(256), 0, stream, tab);
  hipLaunchKernelGGL(k_cvtw, dim3(3072),  dim3(256), 0, stream, wq, wk, wv, wb);
  hipLaunchKernelGGL(k_gemm, dim3(384),   dim3(256), 0, stream, x, wb, tab, qb, kb, vt);
  hipLaunchKernelGGL(k_attn, dim3(1024),  dim3(256), 0, stream, qb, kb, vt, Opart, ml);
  hipLaunchKernelGGL(k_comb, dim3(2048),  dim3(256), 0, stream, Opart, ml, out);
}